// Round 10
// baseline (260.814 us; speedup 1.0000x reference)
//
#include <hip/hip_runtime.h>

// ChannelBlockImportanceGate: B=8, C=256, H=W=132, BLOCK=8, KEEP_RATIO=0.25
// Output = hard top-72 block mask (of 289 blocks) upsampled 8x, per (b,c) plane.
// Straight-through soft blend cancels numerically -> output is the hard mask.
//
// v10 = v9 with Phase C replaced by wave-0 RADIX SELECT (probe-as-
// optimization: measures the true cost of the old all-pairs rank).
//  A: coalesced float4 stream -> f32 |sum| per float4 -> LDS bin (v9).
//  B: per-block 16-bin f64 reduce -> f32-bit u32 keys (v9).
//  C: wave 0 holds all 320 keys (5/lane); 32-bit radix select via
//     __ballot/__popcll finds T = 72nd-largest key and kT = slots left for
//     ties; mask = (key>T) | (key==T & stable-index-order slot < kT).
//     Tie scan is scalar and runs only on tied items (typically 1).
//  D: NT float4 upsample stores (v9).
// LDS ~19.9KB -> 8 blocks/CU.

#define HH 132
#define WW 132
#define NB 17            // blocks per side
#define TOTAL 289        // NB*NB
#define NPAD 320         // padded keys (5 regs x 64 lanes)
#define KEEP 72          // round(289*0.25)
#define NTH 256
#define NC4 33           // float4s per row (132/4)
#define NV 4356          // float4s per plane
#define PLANES 2048

typedef float floatx4 __attribute__((ext_vector_type(4)));

__global__ __launch_bounds__(NTH)
void gate_kernel(const float4* __restrict__ feats4,
                 const int* __restrict__ enabled_p,
                 float4* __restrict__ out4) {
    const int plane = blockIdx.x;
    const int t = threadIdx.x;
    const float4* __restrict__ fp = feats4 + (size_t)plane * NV;

    __shared__ __align__(16) float    s_e[NV];       // 17424 B
    __shared__ __align__(16) unsigned s_key[NPAD];   // 1280 B
    __shared__ float s_hard[TOTAL];                  // 1156 B
    __shared__ unsigned s_T;
    __shared__ int s_kT;

    // ---- Phase A: coalesced stream, per-float4 f32 |sum| -> LDS bin ----
    #pragma unroll
    for (int k = 0; k < 18; ++k) {
        const int v = t + k * NTH;                   // 18*256 covers 4356
        if (v < NV) {
            const float4 x = fp[v];
            s_e[v] = (fabsf(x.x) + fabsf(x.y)) + (fabsf(x.z) + fabsf(x.w));
        }
    }
    __syncthreads();

    // ---- Phase B: block scores (16 bins; right edge 8; bottom 8/4) ----
    // Key = f32 bits of the non-negative score: order-monotone as u32.
    for (int b = t; b < NPAD; b += NTH) {
        unsigned key = 0u;
        if (b < TOTAL) {
            const int br = b / NB;                   // magic-mul
            const int bc = b - br * NB;
            const int nr = (br == NB - 1) ? 4 : 8;   // bottom stripe: 4 rows
            const int base = (br * 8) * NC4 + 2 * bc;
            double sum = 0.0;
            if (bc < NB - 1) {
                for (int rr = 0; rr < nr; ++rr)
                    sum += (double)s_e[base + rr * NC4]
                         + (double)s_e[base + rr * NC4 + 1];
            } else {
                for (int rr = 0; rr < nr; ++rr)
                    sum += (double)s_e[base + rr * NC4];
            }
            key = __float_as_uint((float)sum);
        }
        s_key[b] = key;                              // pads (289..319) = 0
    }
    __syncthreads();

    // ---- Phase C: radix select in wave 0 ----
    // Finds T = 72nd largest of the 320 keys (pads=0 can't displace real
    // keys: ties resolve by index and pads sit at indices >= 289) and
    // kT = number of slots for keys == T, in index order.
    if (t < 64) {
        unsigned K0 = s_key[t];
        unsigned K1 = s_key[64 + t];
        unsigned K2 = s_key[128 + t];
        unsigned K3 = s_key[192 + t];
        unsigned K4 = s_key[256 + t];
        unsigned P = 0u;
        int k = KEEP;
        #pragma unroll
        for (int b = 31; b >= 0; --b) {
            const unsigned hi = (P >> b) | 1u;
            int cnt = __popcll(__ballot((K0 >> b) == hi))
                    + __popcll(__ballot((K1 >> b) == hi))
                    + __popcll(__ballot((K2 >> b) == hi))
                    + __popcll(__ballot((K3 >> b) == hi))
                    + __popcll(__ballot((K4 >> b) == hi));
            if (cnt >= k) P |= (1u << b);
            else          k -= cnt;
        }
        if (t == 0) { s_T = P; s_kT = k; }
    }
    __syncthreads();

    // ---- Mask: key>T keeps; key==T keeps first kT in index order ----
    const int en = *enabled_p;
    const unsigned T = s_T;
    const int kT = s_kT;
    for (int i = t; i < TOTAL; i += NTH) {
        const unsigned ki = s_key[i];
        float m;
        if (!en || ki > T) {
            m = 1.0f;
        } else if (ki < T) {
            m = 0.0f;
        } else {                                     // tie (rare): stable order
            int eq = 0;
            for (int j = 0; j < i; ++j) eq += (int)(s_key[j] == T);
            m = (eq < kT) ? 1.0f : 0.0f;
        }
        s_hard[i] = m;
    }
    __syncthreads();

    // ---- Phase D: upsample 8x, nontemporal float4 stores ----
    floatx4* __restrict__ op = (floatx4*)(out4 + (size_t)plane * NV);
    for (int v = t; v < NV; v += NTH) {
        const int base = v * 4;
        const int row = base / WW;                   // magic-mul
        const int col = base - row * WW;
        const float m = s_hard[(row >> 3) * NB + (col >> 3)];
        const floatx4 mv = {m, m, m, m};
        __builtin_nontemporal_store(mv, &op[v]);
    }
}

extern "C" void kernel_launch(void* const* d_in, const int* in_sizes, int n_in,
                              void* d_out, int out_size, void* d_ws, size_t ws_size,
                              hipStream_t stream) {
    const float4* feats = (const float4*)d_in[0];
    const int* enabled = (const int*)d_in[1];
    float4* out = (float4*)d_out;
    gate_kernel<<<PLANES, NTH, 0, stream>>>(feats, enabled, out);
}

// Round 11
// 259.674 us; speedup vs baseline: 1.0044x; 1.0044x over previous
//
#include <hip/hip_runtime.h>

// ChannelBlockImportanceGate: B=8, C=256, H=W=132, BLOCK=8, KEEP_RATIO=0.25
// Output = hard top-72 block mask (of 289 blocks) upsampled 8x, per (b,c) plane.
// Straight-through soft blend cancels numerically -> output is the hard mask.
//
// v11 = v10 (radix select, f32 bins) with phases A/D restructured for MLP.
// Evidence: v10 VALUBusy 8% + dur unchanged -> compute never mattered; the
// invariant ~2 TB/s read floor across 10 variants tracks VGPR_Count=32: the
// compiler kept only ~2-4 loads in flight (load->wait->ds_write chains).
// Fix (m13 copy-kernel shape): __launch_bounds__(256,1) lifts the register
// cap; Phase A loads all 17 float4s into an explicit register batch (17
// back-to-back global_load_dwordx4, ~17KB/wave in flight) before any
// consumer; Phase D batches LDS mask reads to regs, then 17 back-to-back NT
// stores.

#define HH 132
#define WW 132
#define NB 17            // blocks per side
#define TOTAL 289        // NB*NB
#define NPAD 320         // padded keys (5 regs x 64 lanes)
#define KEEP 72          // round(289*0.25)
#define NTH 256
#define NC4 33           // float4s per row (132/4)
#define NV 4356          // float4s per plane
#define NFULL 17         // full grid-stride steps: 17*256 = 4352
#define PLANES 2048

typedef float floatx4 __attribute__((ext_vector_type(4)));

__global__ __launch_bounds__(NTH, 1)
void gate_kernel(const float4* __restrict__ feats4,
                 const int* __restrict__ enabled_p,
                 float4* __restrict__ out4) {
    const int plane = blockIdx.x;
    const int t = threadIdx.x;
    const float4* __restrict__ fp = feats4 + (size_t)plane * NV;

    __shared__ __align__(16) float    s_e[NV];       // 17424 B
    __shared__ __align__(16) unsigned s_key[NPAD];   // 1280 B
    __shared__ float s_hard[TOTAL];                  // 1156 B
    __shared__ unsigned s_T;
    __shared__ int s_kT;

    // ---- Phase A: register-batched coalesced stream -> f32 |sum| bins ----
    {
        float4 x[NFULL];
        #pragma unroll
        for (int k = 0; k < NFULL; ++k)
            x[k] = fp[t + k * NTH];                  // 17 loads in flight
        float4 xt;
        if (t < NV - NFULL * NTH)                    // 4 tail float4s
            xt = fp[NFULL * NTH + t];
        #pragma unroll
        for (int k = 0; k < NFULL; ++k)
            s_e[t + k * NTH] = (fabsf(x[k].x) + fabsf(x[k].y))
                             + (fabsf(x[k].z) + fabsf(x[k].w));
        if (t < NV - NFULL * NTH)
            s_e[NFULL * NTH + t] = (fabsf(xt.x) + fabsf(xt.y))
                                 + (fabsf(xt.z) + fabsf(xt.w));
    }
    __syncthreads();

    // ---- Phase B: block scores (16 bins; right edge 8; bottom 8/4) ----
    // Key = f32 bits of the non-negative score: order-monotone as u32.
    for (int b = t; b < NPAD; b += NTH) {
        unsigned key = 0u;
        if (b < TOTAL) {
            const int br = b / NB;                   // magic-mul
            const int bc = b - br * NB;
            const int nr = (br == NB - 1) ? 4 : 8;   // bottom stripe: 4 rows
            const int base = (br * 8) * NC4 + 2 * bc;
            double sum = 0.0;
            if (bc < NB - 1) {
                for (int rr = 0; rr < nr; ++rr)
                    sum += (double)s_e[base + rr * NC4]
                         + (double)s_e[base + rr * NC4 + 1];
            } else {
                for (int rr = 0; rr < nr; ++rr)
                    sum += (double)s_e[base + rr * NC4];
            }
            key = __float_as_uint((float)sum);
        }
        s_key[b] = key;                              // pads (289..319) = 0
    }
    __syncthreads();

    // ---- Phase C: radix select in wave 0 (verified v10) ----
    if (t < 64) {
        unsigned K0 = s_key[t];
        unsigned K1 = s_key[64 + t];
        unsigned K2 = s_key[128 + t];
        unsigned K3 = s_key[192 + t];
        unsigned K4 = s_key[256 + t];
        unsigned P = 0u;
        int k = KEEP;
        #pragma unroll
        for (int b = 31; b >= 0; --b) {
            const unsigned hi = (P >> b) | 1u;
            int cnt = __popcll(__ballot((K0 >> b) == hi))
                    + __popcll(__ballot((K1 >> b) == hi))
                    + __popcll(__ballot((K2 >> b) == hi))
                    + __popcll(__ballot((K3 >> b) == hi))
                    + __popcll(__ballot((K4 >> b) == hi));
            if (cnt >= k) P |= (1u << b);
            else          k -= cnt;
        }
        if (t == 0) { s_T = P; s_kT = k; }
    }
    __syncthreads();

    // ---- Mask: key>T keeps; key==T keeps first kT in index order ----
    const int en = *enabled_p;
    const unsigned T = s_T;
    const int kT = s_kT;
    for (int i = t; i < TOTAL; i += NTH) {
        const unsigned ki = s_key[i];
        float m;
        if (!en || ki > T) {
            m = 1.0f;
        } else if (ki < T) {
            m = 0.0f;
        } else {                                     // tie (rare): stable order
            int eq = 0;
            for (int j = 0; j < i; ++j) eq += (int)(s_key[j] == T);
            m = (eq < kT) ? 1.0f : 0.0f;
        }
        s_hard[i] = m;
    }
    __syncthreads();

    // ---- Phase D: batch mask reads to regs, then 17 NT stores ----
    floatx4* __restrict__ op = (floatx4*)(out4 + (size_t)plane * NV);
    {
        float m[NFULL];
        #pragma unroll
        for (int k = 0; k < NFULL; ++k) {
            const int v = t + k * NTH;
            const int base = v * 4;
            const int row = base / WW;               // magic-mul
            const int col = base - row * WW;
            m[k] = s_hard[(row >> 3) * NB + (col >> 3)];
        }
        #pragma unroll
        for (int k = 0; k < NFULL; ++k) {
            const floatx4 mv = {m[k], m[k], m[k], m[k]};
            __builtin_nontemporal_store(mv, &op[t + k * NTH]);
        }
        if (t < NV - NFULL * NTH) {                  // 4 tail float4s
            const int v = NFULL * NTH + t;
            const int base = v * 4;
            const int row = base / WW;
            const int col = base - row * WW;
            const float mt = s_hard[(row >> 3) * NB + (col >> 3)];
            const floatx4 mv = {mt, mt, mt, mt};
            __builtin_nontemporal_store(mv, &op[v]);
        }
    }
}

extern "C" void kernel_launch(void* const* d_in, const int* in_sizes, int n_in,
                              void* d_out, int out_size, void* d_ws, size_t ws_size,
                              hipStream_t stream) {
    const float4* feats = (const float4*)d_in[0];
    const int* enabled = (const int*)d_in[1];
    float4* out = (float4*)d_out;
    gate_kernel<<<PLANES, NTH, 0, stream>>>(feats, enabled, out);
}